// Round 4
// baseline (389.613 us; speedup 1.0000x reference)
//
#include <hip/hip_runtime.h>

#define B_ 16
#define L_ 2048
#define H_ 512
#define P_ 64

typedef __attribute__((ext_vector_type(4))) float f32x4;
typedef __attribute__((ext_vector_type(8))) short short8;
typedef __attribute__((ext_vector_type(4))) short short4v;
typedef __attribute__((ext_vector_type(8))) __bf16 bf16x8;

#define DEVI static __device__ __forceinline__

// 1/sqrt(64) * log2(e): folded into q so softmax uses exp2 directly
#define QSCALE 0.18033688011112042f

DEVI unsigned short f2bf(float f) {
  union { float f; unsigned u; } x; x.f = f;
  unsigned r = x.u + 0x7FFFu + ((x.u >> 16) & 1u);  // round-to-nearest-even
  return (unsigned short)(r >> 16);
}

DEVI f32x4 mfma16(short8 a, short8 b, f32x4 c) {
  return __builtin_amdgcn_mfma_f32_16x16x32_bf16(
      __builtin_bit_cast(bf16x8, a), __builtin_bit_cast(bf16x8, b), c, 0, 0, 0);
}

DEVI short4v ld4s(const unsigned short* p) {
  return *reinterpret_cast<const short4v*>(p);
}

DEVI short8 pack8(short4v a, short4v b) {
  short8 r;
  r[0] = a[0]; r[1] = a[1]; r[2] = a[2]; r[3] = a[3];
  r[4] = b[0]; r[5] = b[1]; r[6] = b[2]; r[7] = b[3];
  return r;
}

// ---------------------------------------------------------------------------
// K1: q/k/v projections. Block = 64 rows. q scaled by QSCALE; v stored
// transposed per batch (vT[b][p][l]) so K2's PV A-operand is row-readable.
// ---------------------------------------------------------------------------
__global__ __launch_bounds__(256) void k_qkv(
    const float* __restrict__ query,
    const float* __restrict__ Wq, const float* __restrict__ bq,
    const float* __restrict__ Wk, const float* __restrict__ bk,
    const float* __restrict__ Wv, const float* __restrict__ bv,
    unsigned short* __restrict__ qbf, unsigned short* __restrict__ kbf,
    unsigned short* __restrict__ vT)
{
  __shared__ unsigned short WT[192][36];  // [out-col][k-in-chunk], pad 36
  __shared__ unsigned short VS[64][72];   // v tile transposed [p][row-local]
  const int tid = threadIdx.x;
  const int lane = tid & 63;
  const int w = tid >> 6;
  const int g = lane >> 4;
  const int ln = lane & 15;
  const long row0 = (long)blockIdx.x * 64;
  const f32x4 fzero = {0.f, 0.f, 0.f, 0.f};

  f32x4 acc[12];
#pragma unroll
  for (int t = 0; t < 12; ++t) acc[t] = fzero;

  for (int k0 = 0; k0 < H_; k0 += 32) {
    __syncthreads();
#pragma unroll
    for (int i = 0; i < 8; ++i) {
      int idx = tid + 256 * i;           // 0..2047
      int kk = idx >> 6, n = idx & 63;
      int gk = (k0 + kk) * 64 + n;
      WT[n][kk]       = f2bf(Wq[gk]);
      WT[n + 64][kk]  = f2bf(Wk[gk]);
      WT[n + 128][kk] = f2bf(Wv[gk]);
    }
    __syncthreads();
    const float* qp = query + (row0 + 16 * w + ln) * (long)H_ + k0 + 4 * g;
    float4 a0 = *reinterpret_cast<const float4*>(qp);
    float4 a1 = *reinterpret_cast<const float4*>(qp + 16);
    short8 af;
    af[0] = (short)f2bf(a0.x); af[1] = (short)f2bf(a0.y);
    af[2] = (short)f2bf(a0.z); af[3] = (short)f2bf(a0.w);
    af[4] = (short)f2bf(a1.x); af[5] = (short)f2bf(a1.y);
    af[6] = (short)f2bf(a1.z); af[7] = (short)f2bf(a1.w);
#pragma unroll
    for (int t = 0; t < 12; ++t) {
      short8 bfr = pack8(ld4s(&WT[t * 16 + ln][4 * g]),
                         ld4s(&WT[t * 16 + ln][16 + 4 * g]));
      acc[t] = mfma16(af, bfr, acc[t]);
    }
  }

  const long rbase = row0 + 16 * w;
#pragma unroll
  for (int t = 0; t < 4; ++t) {
    float bb = bq[t * 16 + ln];
#pragma unroll
    for (int r = 0; r < 4; ++r)
      qbf[(rbase + 4 * g + r) * P_ + t * 16 + ln] =
          f2bf((acc[t][r] + bb) * QSCALE);
  }
#pragma unroll
  for (int t = 0; t < 4; ++t) {
    float bb = bk[t * 16 + ln];
#pragma unroll
    for (int r = 0; r < 4; ++r)
      kbf[(rbase + 4 * g + r) * P_ + t * 16 + ln] = f2bf(acc[4 + t][r] + bb);
  }
#pragma unroll
  for (int t = 0; t < 4; ++t) {
    float bb = bv[t * 16 + ln];
#pragma unroll
    for (int r = 0; r < 4; ++r)
      VS[t * 16 + ln][16 * w + 4 * g + r] = f2bf(acc[8 + t][r] + bb);
  }
  __syncthreads();
  {
    const int p = tid >> 2;
    const int c0 = (tid & 3) * 16;
    const long bb = row0 >> 11;          // batch (2048 rows per batch)
    const long rl = row0 & 2047;
    unsigned short* dst = vT + bb * (long)(P_ * L_) + (long)p * L_ + rl + c0;
    *reinterpret_cast<short8*>(dst) =
        *reinterpret_cast<const short8*>(&VS[p][c0]);
    *reinterpret_cast<short8*>(dst + 8) =
        *reinterpret_cast<const short8*>(&VS[p][c0 + 8]);
  }
}

// ---------------------------------------------------------------------------
// K2: flash attention. Block = one (batch, 64-q-row) tile, 4 waves x 16 q.
// S^T = K*Q^T so the accumulator's kv-index set equals my_k -> P feeds PV
// from registers. Mask skipped (softmax shift-invariant). exp2 domain.
// ---------------------------------------------------------------------------
__global__ __launch_bounds__(256) void k_attn(
    const unsigned short* __restrict__ qbf,
    const unsigned short* __restrict__ kbf,
    const unsigned short* __restrict__ vT,
    unsigned short* __restrict__ wbf)
{
  __shared__ unsigned short OT[64][72];
  const int tid = threadIdx.x;
  const int lane = tid & 63;
  const int w = tid >> 6;
  const int g = lane >> 4;
  const int ln = lane & 15;
  const int b = blockIdx.x >> 5;
  const int qt = blockIdx.x & 31;
  const unsigned short* qb = qbf + (long)b * (L_ * P_);
  const unsigned short* kb = kbf + (long)b * (L_ * P_);
  const unsigned short* vb = vT + (long)b * (P_ * L_);
  const f32x4 fzero = {0.f, 0.f, 0.f, 0.f};

  const int q = qt * 64 + 16 * w + ln;
  const unsigned short* qp = qb + (long)q * P_;
  const short8 qf0 = pack8(ld4s(qp + 4 * g), ld4s(qp + 16 + 4 * g));
  const short8 qf1 = pack8(ld4s(qp + 32 + 4 * g), ld4s(qp + 48 + 4 * g));

  f32x4 o[4];
#pragma unroll
  for (int t = 0; t < 4; ++t) o[t] = fzero;
  float m_run = -1e30f, l_run = 0.f;

  for (int kv0 = 0; kv0 < L_; kv0 += 64) {
    f32x4 s[4];
#pragma unroll
    for (int t = 0; t < 4; ++t) {
      const unsigned short* kp = kb + (long)(kv0 + 16 * t + ln) * P_;
      short8 kf0 = pack8(ld4s(kp + 4 * g), ld4s(kp + 16 + 4 * g));
      short8 kf1 = pack8(ld4s(kp + 32 + 4 * g), ld4s(kp + 48 + 4 * g));
      s[t] = mfma16(kf0, qf0, fzero);
      s[t] = mfma16(kf1, qf1, s[t]);
    }
    // online softmax (per q-col; state replicated over the 4 lane-groups)
    float mx = -1e30f;
#pragma unroll
    for (int t = 0; t < 4; ++t)
#pragma unroll
      for (int r = 0; r < 4; ++r) mx = fmaxf(mx, s[t][r]);
    mx = fmaxf(mx, __shfl_xor(mx, 16));
    mx = fmaxf(mx, __shfl_xor(mx, 32));
    if (!__all(mx <= m_run)) {
      float mn = fmaxf(m_run, mx);
      float sc = exp2f(m_run - mn);
      l_run *= sc;
#pragma unroll
      for (int t = 0; t < 4; ++t) o[t] = o[t] * sc;
      m_run = mn;
    }
    float p[4][4];
    float ts = 0.f;
#pragma unroll
    for (int t = 0; t < 4; ++t)
#pragma unroll
      for (int r = 0; r < 4; ++r) {
        p[t][r] = exp2f(s[t][r] - m_run);
        ts += p[t][r];
      }
    ts += __shfl_xor(ts, 16);
    ts += __shfl_xor(ts, 32);
    l_run += ts;
    short8 pa0, pa1;
#pragma unroll
    for (int j = 0; j < 4; ++j) {
      pa0[j] = (short)f2bf(p[0][j]);
      pa0[4 + j] = (short)f2bf(p[1][j]);
      pa1[j] = (short)f2bf(p[2][j]);
      pa1[4 + j] = (short)f2bf(p[3][j]);
    }
#pragma unroll
    for (int t = 0; t < 4; ++t) {
      const unsigned short* vp = vb + (long)(16 * t + ln) * L_ + kv0;
      short8 vf0 = pack8(ld4s(vp + 4 * g), ld4s(vp + 16 + 4 * g));
      short8 vf1 = pack8(ld4s(vp + 32 + 4 * g), ld4s(vp + 48 + 4 * g));
      o[t] = mfma16(vf0, pa0, o[t]);
      o[t] = mfma16(vf1, pa1, o[t]);
    }
  }

  const float linv = 1.0f / l_run;
#pragma unroll
  for (int t = 0; t < 4; ++t)
#pragma unroll
    for (int r = 0; r < 4; ++r)
      OT[16 * w + ln][16 * t + 4 * g + r] = f2bf(o[t][r] * linv);
  __syncthreads();
  {
    const int qr = tid >> 2;
    const int c0 = (tid & 3) * 16;
    unsigned short* dst = wbf + ((long)b * L_ + qt * 64 + qr) * P_ + c0;
    *reinterpret_cast<short8*>(dst) =
        *reinterpret_cast<const short8*>(&OT[qr][c0]);
    *reinterpret_cast<short8*>(dst + 8) =
        *reinterpret_cast<const short8*>(&OT[qr][c0 + 8]);
  }
}

// ---------------------------------------------------------------------------
// K3: out = weighted @ Wo + bo. Wo^T staged in exactly 64KB LDS with an XOR
// swizzle on 4-short groups (linear layout would be a 16-way bank conflict).
// ---------------------------------------------------------------------------
__global__ __launch_bounds__(256) void k_out(
    const unsigned short* __restrict__ wbf,
    const float* __restrict__ Wo, const float* __restrict__ bo,
    float* __restrict__ out)
{
  __shared__ unsigned short WoT[512][64];  // 64 KB, swizzled
  const int tid = threadIdx.x;
  const int lane = tid & 63;
  const int w = tid >> 6;
  const int g = lane >> 4;
  const int ln = lane & 15;
  const long row0 = (long)blockIdx.x * 64;
  const f32x4 fzero = {0.f, 0.f, 0.f, 0.f};

#pragma unroll
  for (int i = 0; i < 32; ++i) {
    int idx4 = (tid + 256 * i) * 4;      // element index into Wo[64][512]
    float4 v = *reinterpret_cast<const float4*>(Wo + idx4);
    int k = idx4 >> 9;
    int n = idx4 & 511;
    int cg = k >> 2, kl = k & 3;
    WoT[n][((cg ^ (n & 15)) << 2) + kl] = f2bf(v.x);
    WoT[n + 1][((cg ^ ((n + 1) & 15)) << 2) + kl] = f2bf(v.y);
    WoT[n + 2][((cg ^ ((n + 2) & 15)) << 2) + kl] = f2bf(v.z);
    WoT[n + 3][((cg ^ ((n + 3) & 15)) << 2) + kl] = f2bf(v.w);
  }
  __syncthreads();

  const unsigned short* ap = wbf + (row0 + 16 * w + ln) * P_;
  const short8 af0 = pack8(ld4s(ap + 4 * g), ld4s(ap + 16 + 4 * g));
  const short8 af1 = pack8(ld4s(ap + 32 + 4 * g), ld4s(ap + 48 + 4 * g));

  for (int t = 0; t < 32; ++t) {
    const int n0 = t * 16;
    const int n = n0 + ln;               // n & 15 == ln
    short8 b0 = pack8(ld4s(&WoT[n][(g ^ ln) << 2]),
                      ld4s(&WoT[n][((4 + g) ^ ln) << 2]));
    short8 b1 = pack8(ld4s(&WoT[n][((8 + g) ^ ln) << 2]),
                      ld4s(&WoT[n][((12 + g) ^ ln) << 2]));
    f32x4 acc = mfma16(af0, b0, fzero);
    acc = mfma16(af1, b1, acc);
    const float bb = bo[n];
#pragma unroll
    for (int r = 0; r < 4; ++r)
      out[(row0 + 16 * w + 4 * g + r) * (long)H_ + n] = acc[r] + bb;
  }
}

extern "C" void kernel_launch(void* const* d_in, const int* in_sizes, int n_in,
                              void* d_out, int out_size, void* d_ws, size_t ws_size,
                              hipStream_t stream)
{
  const float* query = (const float*)d_in[0];
  // d_in[1] = attention_mask: mathematically a no-op (constant shift per
  // softmax row over the key axis) -> intentionally unused.
  const float* Wq = (const float*)d_in[2];
  const float* bq = (const float*)d_in[3];
  const float* Wk = (const float*)d_in[4];
  const float* bk = (const float*)d_in[5];
  const float* Wv = (const float*)d_in[6];
  const float* bv = (const float*)d_in[7];
  const float* Wo = (const float*)d_in[8];
  const float* bo = (const float*)d_in[9];
  float* out = (float*)d_out;

  const long M = (long)B_ * L_;          // 32768 rows
  unsigned short* qbf = (unsigned short*)d_ws;          // 4 MB
  unsigned short* kbf = qbf + M * P_;                   // 4 MB
  unsigned short* vTp = kbf + M * P_;                   // 4 MB (transposed v)
  unsigned short* wbf = vTp + M * P_;                   // 4 MB

  k_qkv<<<dim3(M / 64), dim3(256), 0, stream>>>(
      query, Wq, bq, Wk, bk, Wv, bv, qbf, kbf, vTp);
  k_attn<<<dim3(B_ * (L_ / 64)), dim3(256), 0, stream>>>(qbf, kbf, vTp, wbf);
  k_out<<<dim3(M / 64), dim3(256), 0, stream>>>(wbf, Wo, bo, out);
}